// Round 8
// baseline (345.426 us; speedup 1.0000x reference)
//
#include <hip/hip_runtime.h>
#include <cstdint>
#include <cstddef>

// Problem constants
#define BB    8
#define HH    32
#define WW    32
#define TT    4
#define DD    768
#define N0    1408
#define N1    336
#define N2    84
#define NTOK  1828
#define TOK_FLOATS (BB*NTOK*DD)        // 11231232
#define KDIM  3072                     // 4 pixels * 768 ch
#define M1    (BB*N1)                  // 2688
#define M2A   (BB*N2*4)                // 2688
#define M2B   (BB*N2)                  // 672

typedef __attribute__((ext_vector_type(8)))  short          short8v;  // 8 bf16 MFMA frag
typedef __attribute__((ext_vector_type(8)))  unsigned short us8;      // 16B
typedef __attribute__((ext_vector_type(4)))  unsigned short us4;      // 8B
typedef __attribute__((ext_vector_type(16))) float          f32x16;   // 32x32 acc

__device__ __forceinline__ unsigned short f2bf(float f) {   // RNE fp32->bf16
    unsigned int u = __float_as_uint(f);
    u += 0x7fffu + ((u >> 16) & 1u);
    return (unsigned short)(u >> 16);
}

// async 16B global->LDS DMA (LDS dest: wave-uniform base + lane*16)
__device__ __forceinline__ void cp16(const unsigned short* g, unsigned short* l) {
    __builtin_amdgcn_global_load_lds(
        (const __attribute__((address_space(1))) unsigned int*)(const void*)g,
        (__attribute__((address_space(3))) unsigned int*)(void*)l,
        16, 0, 0);
}

// ---------------------------------------------------------------------------
// prep mega-kernel (batched-MLP version):
//   gatherA  1008 blk : A rows bf16 [m][3072], 256B loads/thread, pre-swizzled
//   castW    1728 blk : 3 weights -> [n][k] bf16, octet-swizzled by n&7
//   zero      504 blk : zero mode-2 out region (stage-b atomicAdd target)
//   positions   8 blk
// Swizzle (validated r7): within each 128B (8-octet) k-segment of row r,
// stored octet o holds source octet o ^ (r&7)   (involution)
// ---------------------------------------------------------------------------
#define GA_BLKS 1008
#define CW_BLKS 1728
#define Z_BLKS  504
#define PREP_BLKS (GA_BLKS + CW_BLKS + Z_BLKS + 8)   // 3248

__global__ __launch_bounds__(256) void prep_kernel(
    const float* __restrict__ base, const int* __restrict__ d0,
    const int* __restrict__ d1, const int* __restrict__ d2,
    const float* __restrict__ w1, const float* __restrict__ w2a,
    const float* __restrict__ w2b,
    unsigned short* __restrict__ A1, unsigned short* __restrict__ A2,
    unsigned short* __restrict__ W1, unsigned short* __restrict__ W2a,
    unsigned short* __restrict__ W2b,
    float* __restrict__ out, float* __restrict__ pos)
{
    const int blk = blockIdx.x, tid = threadIdx.x;
    if (blk < GA_BLKS) {
        // ---- gatherA: thread = one 8-octet (64-float) segment of one A row
        int idx = blk * 256 + tid;            // 0..258047
        int rm = idx / 48, sg = idx - rm * 48;
        int key = rm & 7;
        int p = sg / 12, cb = (sg - p * 12) * 64;   // pixel, float col base
        const float* rowp;
        unsigned short* dst;
        if (rm < M1) {
            int m = rm, b = m / N1, tok = m - b * N1;
            int y = d1[tok*3] + (p>>1), x = d1[tok*3+1] + (p&1), t = d1[tok*3+2];
            rowp = base + (size_t)(((b*HH + y)*WW + x)*TT + t) * DD;
            dst  = A1 + (size_t)m * KDIM + sg * 64;
        } else {
            int m = rm - M1, b = m / (N2*4), r = m - b * (N2*4);
            int n = r >> 2, hw = r & 3, h = hw >> 1, w = hw & 1;
            int y = d2[n*3] + 2*h + (p>>1), x = d2[n*3+1] + 2*w + (p&1), t = d2[n*3+2];
            rowp = base + (size_t)(((b*HH + y)*WW + x)*TT + t) * DD;
            dst  = A2 + (size_t)m * KDIM + sg * 64;
        }
        float4 v[16];
        #pragma unroll
        for (int j = 0; j < 16; ++j) v[j] = *(const float4*)(rowp + cb + j*4);
        #pragma unroll
        for (int o = 0; o < 8; ++o) {         // dst octet o <- src octet o^key
            int s = o ^ key;
            float4 lo = v[s*2], hi = v[s*2+1];
            us8 r8;
            r8[0]=f2bf(lo.x); r8[1]=f2bf(lo.y); r8[2]=f2bf(lo.z); r8[3]=f2bf(lo.w);
            r8[4]=f2bf(hi.x); r8[5]=f2bf(hi.y); r8[6]=f2bf(hi.z); r8[7]=f2bf(hi.w);
            *(us8*)(dst + o*8) = r8;
        }
    } else if (blk < GA_BLKS + CW_BLKS) {
        // ---- castW: thread = (d, 4-channel group cg); w[d][c][i][j] -> Wt[d][p*768+c']
        int r = blk - GA_BLKS;
        int wsel = r / 576;
        int idx  = (r - wsel * 576) * 256 + tid;     // 0..147455
        const float* w     = wsel==0 ? w1 : (wsel==1 ? w2a : w2b);
        unsigned short* Wt = wsel==0 ? W1 : (wsel==1 ? W2a : W2b);
        int d = idx / 192, cg = idx - d * 192;
        const float* src = w + (size_t)d * KDIM + cg * 16;
        float4 v0 = ((const float4*)src)[0];   // channel cg*4+0, p=0..3
        float4 v1 = ((const float4*)src)[1];
        float4 v2 = ((const float4*)src)[2];
        float4 v3 = ((const float4*)src)[3];
        int csw = ((cg*4) & ~63) | ((((cg>>1) ^ d) & 7) << 3) | ((cg & 1) * 4);
        unsigned short* ob = Wt + (size_t)d * KDIM + csw;
        float pv[4][4] = {{v0.x,v1.x,v2.x,v3.x},{v0.y,v1.y,v2.y,v3.y},
                          {v0.z,v1.z,v2.z,v3.z},{v0.w,v1.w,v2.w,v3.w}};
        #pragma unroll
        for (int p = 0; p < 4; ++p) {
            us4 o4; o4[0]=f2bf(pv[p][0]); o4[1]=f2bf(pv[p][1]);
                    o4[2]=f2bf(pv[p][2]); o4[3]=f2bf(pv[p][3]);
            *(us4*)(ob + p*DD) = o4;
        }
    } else if (blk < GA_BLKS + CW_BLKS + Z_BLKS) {
        // ---- zero mode-2 out region (atomicAdd target; out is poisoned 0xAA)
        int g = (blk - GA_BLKS - CW_BLKS) * 256 + tid;   // 0..129023
        int d4 = g % 192, r = g / 192;
        int tk = r % N2, b = r / N2;
        float4 z = {0.f, 0.f, 0.f, 0.f};
        *(float4*)(out + ((size_t)b*NTOK + N0 + N1 + tk)*DD + d4*4) = z;
    } else {
        // ---- positions (float values; validated r5)
        int n = (blk - GA_BLKS - CW_BLKS - Z_BLKS) * 256 + tid;
        if (n >= NTOK) return;
        int y, x, t, s;
        if (n < N0)         { y = d0[n*3];         x = d0[n*3+1];         t = d0[n*3+2];       s = 1; }
        else if (n < N0+N1) { int m = n - N0;      y = d1[m*3]; x = d1[m*3+1]; t = d1[m*3+2];  s = 2; }
        else                { int m = n - N0 - N1; y = d2[m*3]; x = d2[m*3+1]; t = d2[m*3+2];  s = 4; }
        pos[n*4+0] = (float)y; pos[n*4+1] = (float)x; pos[n*4+2] = (float)s; pos[n*4+3] = (float)t;
    }
}

// ---------------------------------------------------------------------------
// bf16 MFMA GEMM v4: 32x32x16 frags, block 128x128, 4 waves (2x2), wave 64x64.
// DMA (global_load_lds 16B) double-buffer, counted vmcnt(8), raw s_barrier.
// Workspace pre-swizzled (octet ^= row&7 per 128B segment); reads XOR back.
// A-frag: lane holds A[l&31][(l>>5)*8+j]; C/D: col=l&31, row=(reg&3)+8*(reg>>2)+4*(l>>5).
// modes: 0 tokens f32 store | 1 y1b bf16 store (key (m>>2)&7) | 2 atomicAdd f32
// Blocks >= ngemm are LDS-free tok0-copy blocks (overlap HBM under LDS-bound GEMM).
// ---------------------------------------------------------------------------
struct GCfg {
    const unsigned short* A;
    const unsigned short* Bw;
    const float*          bias;
    float*                outf;
    unsigned short*       outb;
    int                   M;
    int                   mode;
    int                   kbeg;
    int                   kend;
};

__global__ __launch_bounds__(256) void mfma_gemm_v4(
    GCfg c0, GCfg c1, int nper, int mblks, int ngemm,
    const float* __restrict__ base, const int* __restrict__ d0,
    float* __restrict__ out0)
{
    if ((int)blockIdx.x >= ngemm) {
        // ---- tok0 copy block: thread = 64 floats of one token row
        int g = ((int)blockIdx.x - ngemm) * 256 + threadIdx.x;  // 0..135167
        int r = g / 12, q = g - r * 12;
        int b = r / N0, n = r - b * N0;
        int y = d0[n*3], x = d0[n*3+1], t = d0[n*3+2];
        const float4* src = (const float4*)(base + (size_t)(((b*HH + y)*WW + x)*TT + t) * DD + q*64);
        float4*       dst = (float4*)(out0 + ((size_t)b*NTOK + n) * DD + q*64);
        float4 v[16];
        #pragma unroll
        for (int j = 0; j < 16; ++j) v[j] = src[j];
        #pragma unroll
        for (int j = 0; j < 16; ++j) dst[j] = v[j];
        return;
    }

    __shared__ unsigned short As[2][128 * 64];   // 2 x 16 KB
    __shared__ unsigned short Bs[2][128 * 64];   // 2 x 16 KB

    // bijective XCD-chunked swizzle (m204) over the gemm range
    int wgid;
    {
        int nwg = ngemm, orig = blockIdx.x;
        int q = nwg >> 3, r = nwg & 7;
        int xcd = orig & 7, k = orig >> 3;
        wgid = (xcd < r ? xcd * (q + 1) : r * (q + 1) + (xcd - r) * q) + k;
    }
    GCfg cfg = c0;
    if (wgid >= nper) { cfg = c1; wgid -= nper; }
    const int nb = wgid / mblks, mb = wgid - nb * mblks;
    const int m0 = mb * 128, n0 = nb * 128;

    const int tid = threadIdx.x, lane = tid & 63;
    const int wv = tid >> 6, wr = wv >> 1, wc = wv & 1;   // 2x2 wave grid
    const int l31 = lane & 31, l5 = lane >> 5;

    // DMA: round j covers tile rows j*32..j*32+31; lane covers (row tid>>3, oct tid&7)
    const unsigned short* agp[4];
    const unsigned short* bgp[4];
    #pragma unroll
    for (int j = 0; j < 4; ++j) {
        int ar = m0 + j*32 + (tid >> 3); if (ar >= cfg.M) ar = cfg.M - 1;
        agp[j] = cfg.A  + (size_t)ar * KDIM + cfg.kbeg + (tid & 7) * 8;
        int br = n0 + j*32 + (tid >> 3);
        bgp[j] = cfg.Bw + (size_t)br * KDIM + cfg.kbeg + (tid & 7) * 8;
    }
    const int wb = (tid >> 6) * 512;   // wave-uniform LDS base (8 rows * 64)

    f32x16 acc[2][2];
    #pragma unroll
    for (int i = 0; i < 2; ++i)
        #pragma unroll
        for (int j = 0; j < 2; ++j)
            #pragma unroll
            for (int r = 0; r < 16; ++r) acc[i][j][r] = 0.f;

    auto STAGE = [&](int buf, int k0) {
        #pragma unroll
        for (int j = 0; j < 4; ++j) cp16(agp[j] + k0, &As[buf][j*2048 + wb]);
        #pragma unroll
        for (int j = 0; j < 4; ++j) cp16(bgp[j] + k0, &Bs[buf][j*2048 + wb]);
    };

    const int NIT = (cfg.kend - cfg.kbeg) >> 6;
    STAGE(0, 0);
    for (int it = 0; it < NIT; ++it) {
        const int cur = it & 1;
        if (it + 1 < NIT) {
            STAGE(cur ^ 1, (it + 1) * 64);                  // 8 more in flight
            asm volatile("s_waitcnt vmcnt(8)" ::: "memory"); // cur's 8 landed
        } else {
            asm volatile("s_waitcnt vmcnt(0)" ::: "memory");
        }
        __builtin_amdgcn_s_barrier();
        const unsigned short* Asb = As[cur];
        const unsigned short* Bsb = Bs[cur];
        #pragma unroll
        for (int ks = 0; ks < 4; ++ks) {                    // K=16 per step
            const int q = ks*2 + l5;                        // true octet index
            short8v av[2], bv[2];
            #pragma unroll
            for (int fm = 0; fm < 2; ++fm) {
                int R = wr*64 + fm*32 + l31;
                av[fm] = *(const short8v*)&Asb[R*64 + ((q ^ (R&7)))*8];
            }
            #pragma unroll
            for (int fn = 0; fn < 2; ++fn) {
                int R = wc*64 + fn*32 + l31;
                bv[fn] = *(const short8v*)&Bsb[R*64 + ((q ^ (R&7)))*8];
            }
            #pragma unroll
            for (int fm = 0; fm < 2; ++fm)
                #pragma unroll
                for (int fn = 0; fn < 2; ++fn)
                    acc[fm][fn] = __builtin_amdgcn_mfma_f32_32x32x16_bf16(
                        av[fm], bv[fn], acc[fm][fn], 0, 0, 0);
        }
        __builtin_amdgcn_s_barrier();
    }

    // epilogue: m = m0+wr*64+fm*32+(reg&3)+8*(reg>>2)+4*l5 ; n = n0+wc*64+fn*32+l31
    const int mode = cfg.mode;
    #pragma unroll
    for (int fm = 0; fm < 2; ++fm) {
        #pragma unroll
        for (int fn = 0; fn < 2; ++fn) {
            int n = n0 + wc*64 + fn*32 + l31;
            float bs = cfg.bias[n];
            #pragma unroll
            for (int reg = 0; reg < 16; ++reg) {
                int m = m0 + wr*64 + fm*32 + (reg&3) + 8*(reg>>2) + 4*l5;
                if (m >= cfg.M) continue;
                float v = acc[fm][fn][reg];
                if (mode == 0) {
                    int b = m / N1, tok = m - b*N1;
                    cfg.outf[((size_t)b*NTOK + N0 + tok)*DD + n] = v + bs;
                } else if (mode == 1) {
                    int nsw = (n & ~63) | ((((n>>3) ^ (m>>2)) & 7) << 3) | (n & 7);
                    cfg.outb[(size_t)m*DD + nsw] = f2bf(v + bs);
                } else {
                    int b = m / N2, tk = m - b*N2;
                    float add = v + (cfg.kbeg == 0 ? bs : 0.f);
                    atomicAdd(&cfg.outf[((size_t)b*NTOK + N0 + N1 + tk)*DD + n], add);
                }
            }
        }
    }
}

// ---------------------------------------------------------------------------
extern "C" void kernel_launch(void* const* d_in, const int* in_sizes, int n_in,
                              void* d_out, int out_size, void* d_ws, size_t ws_size,
                              hipStream_t stream)
{
    const float* base  = (const float*)d_in[0];
    const int*   desc0 = (const int*)  d_in[1];
    const int*   desc1 = (const int*)  d_in[2];
    const int*   desc2 = (const int*)  d_in[3];
    const float* w1    = (const float*)d_in[4];
    const float* b1    = (const float*)d_in[5];
    const float* w2a   = (const float*)d_in[6];
    const float* b2a   = (const float*)d_in[7];
    const float* w2b   = (const float*)d_in[8];
    const float* b2b   = (const float*)d_in[9];

    float* out = (float*)d_out;
    float* pos = (float*)d_out + TOK_FLOATS;
    unsigned short* ws = (unsigned short*)d_ws;

    const size_t ABF = (size_t)M1 * KDIM;    // 8257536
    const size_t Y1  = (size_t)M2A * DD;     // 2064384
    const size_t WTB = (size_t)DD * KDIM;    // 2359296
    unsigned short* A1  = ws;
    unsigned short* A2  = A1  + ABF;
    unsigned short* y1b = A2  + ABF;
    unsigned short* W1  = y1b + Y1;
    unsigned short* W2a = W1  + WTB;
    unsigned short* W2b = W2a + WTB;

    prep_kernel<<<PREP_BLKS, 256, 0, stream>>>(
        base, desc0, desc1, desc2, w1, w2a, w2b,
        A1, A2, W1, W2a, W2b, out, pos);

    // fused GEMM1+GEMM2a (2 x 21x6 = 252 gemm blocks) + 528 tok0-copy blocks
    GCfg cA = { A1, W1,  b1,  out,     nullptr, M1,  0, 0, KDIM };
    GCfg cB = { A2, W2a, b2a, nullptr, y1b,     M2A, 1, 0, KDIM };
    mfma_gemm_v4<<<252 + 528, 256, 0, stream>>>(cA, cB, 126, 21, 252, base, desc0, out);

    // stage b: M=672, K-split x2 (6x6 blocks per half), atomicAdd epilogue
    GCfg cC0 = { y1b, W2b, b2b, out, nullptr, M2B, 2, 0,        KDIM/2 };
    GCfg cC1 = { y1b, W2b, b2b, out, nullptr, M2B, 2, KDIM/2,   KDIM   };
    mfma_gemm_v4<<<72, 256, 0, stream>>>(cC0, cC1, 36, 6, 72, base, desc0, out);
}

// Round 9
// 342.670 us; speedup vs baseline: 1.0080x; 1.0080x over previous
//
#include <hip/hip_runtime.h>
#include <cstdint>
#include <cstddef>

// Problem constants
#define BB    8
#define HH    32
#define WW    32
#define TT    4
#define DD    768
#define N0    1408
#define N1    336
#define N2    84
#define NTOK  1828
#define TOK_FLOATS (BB*NTOK*DD)        // 11231232
#define KDIM  3072                     // 4 pixels * 768 ch
#define M1    (BB*N1)                  // 2688
#define M2A   (BB*N2*4)                // 2688
#define M2B   (BB*N2)                  // 672

typedef __attribute__((ext_vector_type(8))) short          short8v; // 8 bf16 MFMA frag
typedef __attribute__((ext_vector_type(8))) unsigned short us8;     // 16B
typedef __attribute__((ext_vector_type(4))) unsigned short us4;     // 8B
typedef __attribute__((ext_vector_type(4))) float          f32x4;   // 16x16 acc

__device__ __forceinline__ unsigned short f2bf(float f) {   // RNE fp32->bf16
    unsigned int u = __float_as_uint(f);
    u += 0x7fffu + ((u >> 16) & 1u);
    return (unsigned short)(u >> 16);
}

// async 16B global->LDS DMA (LDS dest: wave-uniform base + lane*16)
__device__ __forceinline__ void cp16(const unsigned short* g, unsigned short* l) {
    __builtin_amdgcn_global_load_lds(
        (const __attribute__((address_space(1))) unsigned int*)(const void*)g,
        (__attribute__((address_space(3))) unsigned int*)(void*)l,
        16, 0, 0);
}

// ---------------------------------------------------------------------------
// prep mega-kernel (all batched, one launch):
//   gatherA  1008 blk : A rows bf16 [m][3072], 256B loads/thread, pre-swizzled
//   castW    1728 blk : 3 weights -> [n][k] bf16, octet-swizzled by n&7
//   zero      504 blk : zero mode-2 out region (stage-b atomicAdd target)
//   copy0     528 blk : tok0 gather, 256B/thread
//   positions   8 blk
// Swizzle (validated r7/r8): within each 128B (8-octet) k-segment of row r,
// stored octet o holds source octet o ^ (r&7)   (involution)
// ---------------------------------------------------------------------------
#define GA_BLKS 1008
#define CW_BLKS 1728
#define Z_BLKS  504
#define C0_BLKS 528
#define PREP_BLKS (GA_BLKS + CW_BLKS + Z_BLKS + C0_BLKS + 8)   // 3776

__global__ __launch_bounds__(256) void prep_kernel(
    const float* __restrict__ base, const int* __restrict__ d0,
    const int* __restrict__ d1, const int* __restrict__ d2,
    const float* __restrict__ w1, const float* __restrict__ w2a,
    const float* __restrict__ w2b,
    unsigned short* __restrict__ A1, unsigned short* __restrict__ A2,
    unsigned short* __restrict__ W1, unsigned short* __restrict__ W2a,
    unsigned short* __restrict__ W2b,
    float* __restrict__ out, float* __restrict__ pos)
{
    const int blk = blockIdx.x, tid = threadIdx.x;
    if (blk < GA_BLKS) {
        // ---- gatherA: thread = one 8-octet (64-float) segment of one A row
        int idx = blk * 256 + tid;            // 0..258047
        int rm = idx / 48, sg = idx - rm * 48;
        int key = rm & 7;
        int p = sg / 12, cb = (sg - p * 12) * 64;   // pixel, float col base
        const float* rowp;
        unsigned short* dst;
        if (rm < M1) {
            int m = rm, b = m / N1, tok = m - b * N1;
            int y = d1[tok*3] + (p>>1), x = d1[tok*3+1] + (p&1), t = d1[tok*3+2];
            rowp = base + (size_t)(((b*HH + y)*WW + x)*TT + t) * DD;
            dst  = A1 + (size_t)m * KDIM + sg * 64;
        } else {
            int m = rm - M1, b = m / (N2*4), r = m - b * (N2*4);
            int n = r >> 2, hw = r & 3, h = hw >> 1, w = hw & 1;
            int y = d2[n*3] + 2*h + (p>>1), x = d2[n*3+1] + 2*w + (p&1), t = d2[n*3+2];
            rowp = base + (size_t)(((b*HH + y)*WW + x)*TT + t) * DD;
            dst  = A2 + (size_t)m * KDIM + sg * 64;
        }
        float4 v[16];
        #pragma unroll
        for (int j = 0; j < 16; ++j) v[j] = *(const float4*)(rowp + cb + j*4);
        #pragma unroll
        for (int o = 0; o < 8; ++o) {         // dst octet o <- src octet o^key
            int s = o ^ key;
            float4 lo = v[s*2], hi = v[s*2+1];
            us8 r8;
            r8[0]=f2bf(lo.x); r8[1]=f2bf(lo.y); r8[2]=f2bf(lo.z); r8[3]=f2bf(lo.w);
            r8[4]=f2bf(hi.x); r8[5]=f2bf(hi.y); r8[6]=f2bf(hi.z); r8[7]=f2bf(hi.w);
            *(us8*)(dst + o*8) = r8;
        }
    } else if (blk < GA_BLKS + CW_BLKS) {
        // ---- castW: thread = (d, 4-channel group cg); w[d][c][i][j] -> Wt[d][p*768+c']
        int r = blk - GA_BLKS;
        int wsel = r / 576;
        int idx  = (r - wsel * 576) * 256 + tid;     // 0..147455
        const float* w     = wsel==0 ? w1 : (wsel==1 ? w2a : w2b);
        unsigned short* Wt = wsel==0 ? W1 : (wsel==1 ? W2a : W2b);
        int d = idx / 192, cg = idx - d * 192;
        const float* src = w + (size_t)d * KDIM + cg * 16;
        float4 v0 = ((const float4*)src)[0];   // channel cg*4+0, p=0..3
        float4 v1 = ((const float4*)src)[1];
        float4 v2 = ((const float4*)src)[2];
        float4 v3 = ((const float4*)src)[3];
        int csw = ((cg*4) & ~63) | ((((cg>>1) ^ d) & 7) << 3) | ((cg & 1) * 4);
        unsigned short* ob = Wt + (size_t)d * KDIM + csw;
        float pv[4][4] = {{v0.x,v1.x,v2.x,v3.x},{v0.y,v1.y,v2.y,v3.y},
                          {v0.z,v1.z,v2.z,v3.z},{v0.w,v1.w,v2.w,v3.w}};
        #pragma unroll
        for (int p = 0; p < 4; ++p) {
            us4 o4; o4[0]=f2bf(pv[p][0]); o4[1]=f2bf(pv[p][1]);
                    o4[2]=f2bf(pv[p][2]); o4[3]=f2bf(pv[p][3]);
            *(us4*)(ob + p*DD) = o4;
        }
    } else if (blk < GA_BLKS + CW_BLKS + Z_BLKS) {
        // ---- zero mode-2 out region (atomicAdd target; out is poisoned 0xAA)
        int g = (blk - GA_BLKS - CW_BLKS) * 256 + tid;   // 0..129023
        int d4 = g % 192, r = g / 192;
        int tk = r % N2, b = r / N2;
        float4 z = {0.f, 0.f, 0.f, 0.f};
        *(float4*)(out + ((size_t)b*NTOK + N0 + N1 + tk)*DD + d4*4) = z;
    } else if (blk < GA_BLKS + CW_BLKS + Z_BLKS + C0_BLKS) {
        // ---- tok0 copy: thread = 64 floats of one token row (batched)
        int g = (blk - GA_BLKS - CW_BLKS - Z_BLKS) * 256 + tid;  // 0..135167
        int r = g / 12, q = g - r * 12;
        int b = r / N0, n = r - b * N0;
        int y = d0[n*3], x = d0[n*3+1], t = d0[n*3+2];
        const float4* src = (const float4*)(base + (size_t)(((b*HH + y)*WW + x)*TT + t) * DD + q*64);
        float4*       dst = (float4*)(out + ((size_t)b*NTOK + n) * DD + q*64);
        float4 v[16];
        #pragma unroll
        for (int j = 0; j < 16; ++j) v[j] = src[j];
        #pragma unroll
        for (int j = 0; j < 16; ++j) dst[j] = v[j];
    } else {
        // ---- positions (float values; validated r5)
        int n = (blk - GA_BLKS - CW_BLKS - Z_BLKS - C0_BLKS) * 256 + tid;
        if (n >= NTOK) return;
        int y, x, t, s;
        if (n < N0)         { y = d0[n*3];         x = d0[n*3+1];         t = d0[n*3+2];       s = 1; }
        else if (n < N0+N1) { int m = n - N0;      y = d1[m*3]; x = d1[m*3+1]; t = d1[m*3+2];  s = 2; }
        else                { int m = n - N0 - N1; y = d2[m*3]; x = d2[m*3+1]; t = d2[m*3+2];  s = 4; }
        pos[n*4+0] = (float)y; pos[n*4+1] = (float)x; pos[n*4+2] = (float)s; pos[n*4+3] = (float)t;
    }
}

// ---------------------------------------------------------------------------
// bf16 MFMA GEMM v5: r7-validated v3 skeleton, BN shrunk for TLP.
// BM=64 BN=64 BK=64, 256 thr = 4 waves (2x2), wave tile 32x32 (2x2 16x16 frags).
// LDS 32KB -> ~4-5 blocks/CU (grid 1008 ~= 4/CU, 16 waves/CU latency hiding —
// r8 lesson: TLP, not FLOP/LDS-byte, is the binder at this size).
// DMA global_load_lds double-buffer, counted vmcnt(4), raw s_barrier pair.
// Workspace pre-swizzled (octet ^= row&7 per 128B seg); frag reads XOR back.
// modes: 0 tokens f32 | 1 y1b bf16 (key (m>>2)&7) | 2 atomicAdd f32 (K-split)
// ---------------------------------------------------------------------------
struct GCfg {
    const unsigned short* A;
    const unsigned short* Bw;
    const float*          bias;
    float*                outf;
    unsigned short*       outb;
    int                   M;
    int                   mode;
    int                   kbeg;
    int                   kend;
};

__global__ __launch_bounds__(256) void mfma_gemm_v5(
    GCfg c0, GCfg c1, int nper, int mblks)
{
    __shared__ unsigned short As[2][64 * 64];   // 2 x 8 KB
    __shared__ unsigned short Bs[2][64 * 64];   // 2 x 8 KB

    // bijective XCD-chunked swizzle (m204)
    int wgid;
    {
        int nwg = gridDim.x, orig = blockIdx.x;
        int q = nwg >> 3, r = nwg & 7;
        int xcd = orig & 7, k = orig >> 3;
        wgid = (xcd < r ? xcd * (q + 1) : r * (q + 1) + (xcd - r) * q) + k;
    }
    GCfg cfg = c0;
    if (wgid >= nper) { cfg = c1; wgid -= nper; }
    const int nb = wgid / mblks, mb = wgid - nb * mblks;
    const int m0 = mb * 64, n0 = nb * 64;

    const int tid = threadIdx.x, lane = tid & 63;
    const int wv = tid >> 6, wr = wv >> 1, wc = wv & 1;   // 2x2 wave grid
    const int lr = lane & 15, lq = lane >> 4, xr = lr & 7;

    // DMA: 2 A rounds + 2 B rounds; round j covers tile rows j*32+(tid>>3)
    int ar0 = m0 +      (tid >> 3); if (ar0 >= cfg.M) ar0 = cfg.M - 1;
    int ar1 = m0 + 32 + (tid >> 3); if (ar1 >= cfg.M) ar1 = cfg.M - 1;
    const unsigned short* ag0 = cfg.A  + (size_t)ar0 * KDIM + cfg.kbeg + (tid & 7) * 8;
    const unsigned short* ag1 = cfg.A  + (size_t)ar1 * KDIM + cfg.kbeg + (tid & 7) * 8;
    const unsigned short* bg0 = cfg.Bw + (size_t)(n0 +      (tid >> 3)) * KDIM + cfg.kbeg + (tid & 7) * 8;
    const unsigned short* bg1 = cfg.Bw + (size_t)(n0 + 32 + (tid >> 3)) * KDIM + cfg.kbeg + (tid & 7) * 8;
    const int wb = (tid >> 6) * 512;   // wave-uniform LDS ushort base (8 rows)

    f32x4 acc[2][2];
    #pragma unroll
    for (int i = 0; i < 2; ++i)
        #pragma unroll
        for (int j = 0; j < 2; ++j)
            #pragma unroll
            for (int r = 0; r < 4; ++r) acc[i][j][r] = 0.f;

    auto STAGE = [&](int buf, int k0) {
        cp16(ag0 + k0, &As[buf][0*2048 + wb]);
        cp16(ag1 + k0, &As[buf][1*2048 + wb]);
        cp16(bg0 + k0, &Bs[buf][0*2048 + wb]);
        cp16(bg1 + k0, &Bs[buf][1*2048 + wb]);
    };

    const int NIT = (cfg.kend - cfg.kbeg) >> 6;
    STAGE(0, 0);
    for (int it = 0; it < NIT; ++it) {
        const int cur = it & 1;
        if (it + 1 < NIT) {
            STAGE(cur ^ 1, (it + 1) * 64);                  // 4 more in flight
            asm volatile("s_waitcnt vmcnt(4)" ::: "memory"); // cur's 4 landed
        } else {
            asm volatile("s_waitcnt vmcnt(0)" ::: "memory");
        }
        __builtin_amdgcn_s_barrier();
        const unsigned short* Asb = As[cur];
        const unsigned short* Bsb = Bs[cur];
        #pragma unroll
        for (int ks = 0; ks < 2; ++ks) {
            short8v av[2], bv[2];
            #pragma unroll
            for (int fm = 0; fm < 2; ++fm) {
                int row = wr*32 + fm*16 + lr;
                av[fm] = *(const short8v*)&Asb[row*64 + ((ks*4 + lq) ^ xr) * 8];
            }
            #pragma unroll
            for (int fn = 0; fn < 2; ++fn) {
                int row = wc*32 + fn*16 + lr;
                bv[fn] = *(const short8v*)&Bsb[row*64 + ((ks*4 + lq) ^ xr) * 8];
            }
            #pragma unroll
            for (int fm = 0; fm < 2; ++fm)
                #pragma unroll
                for (int fn = 0; fn < 2; ++fn)
                    acc[fm][fn] = __builtin_amdgcn_mfma_f32_16x16x32_bf16(
                        av[fm], bv[fn], acc[fm][fn], 0, 0, 0);
        }
        __builtin_amdgcn_s_barrier();
    }

    // epilogue: m = m0+wr*32+fm*16+lq*4+r ; n = n0+wc*32+fn*16+lr  (r5-validated)
    const int mode = cfg.mode;
    #pragma unroll
    for (int fm = 0; fm < 2; ++fm) {
        #pragma unroll
        for (int fn = 0; fn < 2; ++fn) {
            int n = n0 + wc*32 + fn*16 + lr;
            float bs = cfg.bias[n];
            #pragma unroll
            for (int r = 0; r < 4; ++r) {
                int m = m0 + wr*32 + fm*16 + lq*4 + r;
                if (m >= cfg.M) continue;
                float v = acc[fm][fn][r];
                if (mode == 0) {
                    int b = m / N1, tok = m - b*N1;
                    cfg.outf[((size_t)b*NTOK + N0 + tok)*DD + n] = v + bs;
                } else if (mode == 1) {
                    int nsw = (n & ~63) | ((((n>>3) ^ (m>>2)) & 7) << 3) | (n & 7);
                    cfg.outb[(size_t)m*DD + nsw] = f2bf(v + bs);
                } else {
                    int b = m / N2, tk = m - b*N2;
                    float add = v + (cfg.kbeg == 0 ? bs : 0.f);
                    atomicAdd(&cfg.outf[((size_t)b*NTOK + N0 + N1 + tk)*DD + n], add);
                }
            }
        }
    }
}

// ---------------------------------------------------------------------------
extern "C" void kernel_launch(void* const* d_in, const int* in_sizes, int n_in,
                              void* d_out, int out_size, void* d_ws, size_t ws_size,
                              hipStream_t stream)
{
    const float* base  = (const float*)d_in[0];
    const int*   desc0 = (const int*)  d_in[1];
    const int*   desc1 = (const int*)  d_in[2];
    const int*   desc2 = (const int*)  d_in[3];
    const float* w1    = (const float*)d_in[4];
    const float* b1    = (const float*)d_in[5];
    const float* w2a   = (const float*)d_in[6];
    const float* b2a   = (const float*)d_in[7];
    const float* w2b   = (const float*)d_in[8];
    const float* b2b   = (const float*)d_in[9];

    float* out = (float*)d_out;
    float* pos = (float*)d_out + TOK_FLOATS;
    unsigned short* ws = (unsigned short*)d_ws;

    const size_t ABF = (size_t)M1 * KDIM;    // 8257536
    const size_t Y1  = (size_t)M2A * DD;     // 2064384
    const size_t WTB = (size_t)DD * KDIM;    // 2359296
    unsigned short* A1  = ws;
    unsigned short* A2  = A1  + ABF;
    unsigned short* y1b = A2  + ABF;
    unsigned short* W1  = y1b + Y1;
    unsigned short* W2a = W1  + WTB;
    unsigned short* W2b = W2a + WTB;

    prep_kernel<<<PREP_BLKS, 256, 0, stream>>>(
        base, desc0, desc1, desc2, w1, w2a, w2b,
        A1, A2, W1, W2a, W2b, out, pos);

    // fused GEMM1+GEMM2a: 2 gemms x (12 n-panels x 42 m-blocks) = 1008 blocks
    GCfg cA = { A1, W1,  b1,  out,     nullptr, M1,  0, 0, KDIM };
    GCfg cB = { A2, W2a, b2a, nullptr, y1b,     M2A, 1, 0, KDIM };
    mfma_gemm_v5<<<1008, 256, 0, stream>>>(cA, cB, 504, 42);

    // stage b: M=672, K-split x2: 2 x (12 x 11) = 264 blocks, atomicAdd epilogue
    GCfg cC0 = { y1b, W2b, b2b, out, nullptr, M2B, 2, 0,      KDIM/2 };
    GCfg cC1 = { y1b, W2b, b2b, out, nullptr, M2B, 2, KDIM/2, KDIM   };
    mfma_gemm_v5<<<264, 256, 0, stream>>>(cC0, cC1, 132, 11);
}